// Round 11
// baseline (1113.515 us; speedup 1.0000x reference)
//
#include <hip/hip_runtime.h>

#define HDIM 128
#define TTOK 8
#define NPG 1024
#define NBUCK 512
#define BSHIFT 8
#define BCAP 6144
#define EPB 4096
#define PARTSZ 4160   // per (graph,part): 32*128 O + 32 m + 32 l

typedef unsigned short ushort;
typedef unsigned int uint;
typedef __attribute__((ext_vector_type(8))) short short8;
typedef __attribute__((ext_vector_type(4))) float f32x4;

__device__ __forceinline__ float bf2f(ushort u) {
    return __uint_as_float(((unsigned int)u) << 16);
}
__device__ __forceinline__ ushort f2bf(float f) {
    unsigned int x = __float_as_uint(f);
    return (ushort)((x + 0x7FFFu + ((x >> 16) & 1u)) >> 16);
}
__device__ __forceinline__ float blo(uint u) { return __uint_as_float(u << 16); }
__device__ __forceinline__ float bhi(uint u) { return __uint_as_float(u & 0xFFFF0000u); }
__device__ __forceinline__ uint pk(float a, float b) {
    return (uint)f2bf(a) | ((uint)f2bf(b) << 16);
}

// X trunk layout: 8 planes; plane p holds channels [16p,16p+16) for all N nodes.
// plane stride pls = N*16 ushorts = 4 MiB = one XCD L2.

// ================= binned sort of edges by dst =================
__global__ __launch_bounds__(256) void bin_kernel(const int* __restrict__ src,
    const int* __restrict__ dst, int* __restrict__ bcursor,
    uint* __restrict__ pairbuf, int E)
{
    __shared__ int lcnt[NBUCK];
    __shared__ int lbase[NBUCK];
    int tid = threadIdx.x;
    int e0 = blockIdx.x * EPB;
    for (int i = tid; i < NBUCK; i += 256) lcnt[i] = 0;
    __syncthreads();
    uint pkd[16];
    int bk[16], rk[16];
    #pragma unroll
    for (int i = 0; i < 16; ++i) {
        int e = e0 + i * 256 + tid;
        int s = (e < E) ? src[e] : 0;
        int d = (e < E) ? dst[e] : -1;
        int b = d >> BSHIFT;
        bk[i] = b;
        pkd[i] = ((uint)(d & 255) << 17) | (uint)s;
        rk[i] = (e < E) ? atomicAdd(&lcnt[b], 1) : 0;
    }
    __syncthreads();
    for (int i = tid; i < NBUCK; i += 256) {
        int c = lcnt[i];
        lbase[i] = c ? atomicAdd(&bcursor[i], c) : 0;
    }
    __syncthreads();
    #pragma unroll
    for (int i = 0; i < 16; ++i) {
        if (bk[i] >= 0) {
            int slot = lbase[bk[i]] + rk[i];
            if (slot < BCAP) pairbuf[(size_t)bk[i] * BCAP + slot] = pkd[i];
        }
    }
}

// Pass B: one block per bucket; self-scans bucket counts.
__global__ __launch_bounds__(256) void bucket_sort_kernel(const uint* __restrict__ pairbuf,
    const int* __restrict__ bcount,
    int* __restrict__ ssrc, int* __restrict__ starts, int* __restrict__ countn, int N)
{
    __shared__ int sc[NBUCK];
    __shared__ int lcount[256];
    __shared__ int lcur[256];
    __shared__ int lss[BCAP];   // 24 KB
    int b = blockIdx.x;
    int tid = threadIdx.x;
    sc[tid] = min(bcount[tid], BCAP);
    sc[tid + 256] = min(bcount[tid + 256], BCAP);
    lcount[tid] = 0;
    __syncthreads();
    for (int off = 1; off < NBUCK; off <<= 1) {
        int a0 = (tid >= off) ? sc[tid - off] : 0;
        int a1 = (tid + 256 >= off) ? sc[tid + 256 - off] : 0;
        __syncthreads();
        sc[tid] += a0; sc[tid + 256] += a1;
        __syncthreads();
    }
    int nb = min(bcount[b], BCAP);
    int base = sc[b] - nb;
    const uint* pp = pairbuf + (size_t)b * BCAP;
    for (int i = tid; i < nb; i += 256)
        atomicAdd(&lcount[(pp[i] >> 17) & 255], 1);
    __syncthreads();
    int v = lcount[tid];
    lcur[tid] = v;
    __syncthreads();
    for (int off = 1; off < 256; off <<= 1) {
        int t = (tid >= off) ? lcur[tid - off] : 0;
        __syncthreads();
        lcur[tid] += t;
        __syncthreads();
    }
    int excl = lcur[tid] - v;
    int node = b * 256 + tid;
    starts[node] = base + excl;
    countn[node] = v;
    __syncthreads();
    lcur[tid] = excl;
    __syncthreads();
    for (int i = tid; i < nb; i += 256) {
        uint p = pp[i];
        int pos = atomicAdd(&lcur[(p >> 17) & 255], 1);
        lss[pos] = (int)(p & 0x1FFFFu);
    }
    __syncthreads();
    for (int i = tid; i < nb; i += 256) ssrc[base + i] = lss[i];
    if (b == NBUCK - 1 && tid == 0) starts[N] = base + nb;
}

// ================= f32 -> bf16 convert into plane layout =================
__global__ __launch_bounds__(256) void convert_kernel(const float* __restrict__ in,
                                                      ushort* __restrict__ outb,
                                                      int n16, int pls)
{
    int i = blockIdx.x * 256 + threadIdx.x;
    if (i >= n16) return;
    int n = i >> 4, c8 = i & 15;
    const float* p = in + (size_t)n * 128 + c8 * 8;
    float4 v0 = *(const float4*)p;
    float4 v1 = *(const float4*)(p + 4);
    uint4 o;
    o.x = pk(v0.x, v0.y); o.y = pk(v0.z, v0.w);
    o.z = pk(v1.x, v1.y); o.w = pk(v1.z, v1.w);
    *(uint4*)(outb + (size_t)(c8 >> 1) * pls + (size_t)n * 16 + (c8 & 1) * 8) = o;
}

// ================= sliced gather: slice = blockIdx%8 pins to an XCD =================
// AGG_s[n] = x_s[n] + sum_{e: dst=n} x_s[src[e]]; 64 nodes/block, 4 lanes/node.
__global__ __launch_bounds__(256) void gather_kernel(const ushort* __restrict__ XS,
    const int* __restrict__ ssrc, const int* __restrict__ starts,
    const int* __restrict__ count, ushort* __restrict__ AGG, int pls)
{
    int tid = threadIdx.x;
    int s = blockIdx.x & 7;
    int node = (blockIdx.x >> 3) * 64 + (tid >> 2);
    int lane = tid & 3;
    const ushort* Xp = XS + (size_t)s * pls;
    uint2 sv = *((const uint2*)(Xp + (size_t)node * 16) + lane);
    float a0 = blo(sv.x), a1 = bhi(sv.x), a2 = blo(sv.y), a3 = bhi(sv.y);
    int s0 = starts[node], cn = count[node];
    for (int j0 = 0; j0 < cn; j0 += 4) {
        int myid = (j0 + lane < cn) ? ssrc[s0 + j0 + lane] : 0;
        int m = cn - j0;
        if (m >= 4) {
            int i0 = __shfl(myid, 0, 4), i1 = __shfl(myid, 1, 4);
            int i2 = __shfl(myid, 2, 4), i3 = __shfl(myid, 3, 4);
            uint2 u0 = *((const uint2*)(Xp + (size_t)i0 * 16) + lane);
            uint2 u1 = *((const uint2*)(Xp + (size_t)i1 * 16) + lane);
            uint2 u2 = *((const uint2*)(Xp + (size_t)i2 * 16) + lane);
            uint2 u3 = *((const uint2*)(Xp + (size_t)i3 * 16) + lane);
            a0 += (blo(u0.x) + blo(u1.x)) + (blo(u2.x) + blo(u3.x));
            a1 += (bhi(u0.x) + bhi(u1.x)) + (bhi(u2.x) + bhi(u3.x));
            a2 += (blo(u0.y) + blo(u1.y)) + (blo(u2.y) + blo(u3.y));
            a3 += (bhi(u0.y) + bhi(u1.y)) + (bhi(u2.y) + bhi(u3.y));
        } else {
            for (int j = 0; j < m; ++j) {
                int ii = __shfl(myid, j, 4);
                uint2 u = *((const uint2*)(Xp + (size_t)ii * 16) + lane);
                a0 += blo(u.x); a1 += bhi(u.x); a2 += blo(u.y); a3 += bhi(u.y);
            }
        }
    }
    uint2 o;
    o.x = pk(a0, a1); o.y = pk(a2, a3);
    *((uint2*)(AGG + (size_t)s * pls + (size_t)node * 16) + lane) = o;
}

// ================= MFMA linear (plane bf16 in/out): XD = XS @ W + b [+ GF] =================
__global__ __launch_bounds__(256) void lin128_mfma_kernel(const ushort* __restrict__ XS,
    const float* __restrict__ W, const float* __restrict__ bias,
    const float* __restrict__ GF, ushort* __restrict__ XD, int pls)
{
    __shared__ ushort Xl[128 * 128];
    __shared__ ushort Wl[128 * 128];
    int tid = threadIdx.x;
    size_t r0 = (size_t)blockIdx.x * 128;
    {
        uint4* xl = (uint4*)Xl;
        for (int i = tid; i < 2048; i += 256) {
            int row = i >> 4, cc = i & 15;
            uint4 v = *(const uint4*)(XS + (size_t)(cc >> 1) * pls + (r0 + row) * 16 + (cc & 1) * 8);
            xl[row * 16 + (cc ^ (row & 15))] = v;
        }
    }
    {
        uint4* wl = (uint4*)Wl;
        for (int i = tid; i < 2048; i += 256) {
            int n = i & 127, c = i >> 7;
            const float* wp = W + (size_t)(c * 8) * 128 + n;
            float w0 = wp[0], w1 = wp[128], w2 = wp[256], w3 = wp[384];
            float w4 = wp[512], w5 = wp[640], w6 = wp[768], w7 = wp[896];
            uint4 u;
            u.x = pk(w0, w1); u.y = pk(w2, w3); u.z = pk(w4, w5); u.w = pk(w6, w7);
            wl[n * 16 + (c ^ (n & 15))] = u;
        }
    }
    __syncthreads();
    int wave = tid >> 6;
    int lane = tid & 63;
    int m16 = lane & 15, quad = lane >> 4;
    const short8* Xf = (const short8*)Xl;
    const short8* Wf = (const short8*)Wl;
    short8 afr[2][4];
    #pragma unroll
    for (int rt = 0; rt < 2; ++rt)
        #pragma unroll
        for (int kc = 0; kc < 4; ++kc)
            afr[rt][kc] = Xf[(wave * 32 + rt * 16 + m16) * 16 + ((kc * 4 + quad) ^ m16)];
    int graph = (int)(r0 >> 10);
    #pragma unroll
    for (int ct = 0; ct < 8; ++ct) {
        int col = ct * 16 + m16;
        short8 bfr[4];
        #pragma unroll
        for (int kc = 0; kc < 4; ++kc)
            bfr[kc] = Wf[col * 16 + ((kc * 4 + quad) ^ m16)];
        f32x4 acc0 = {0.f, 0.f, 0.f, 0.f};
        f32x4 acc1 = {0.f, 0.f, 0.f, 0.f};
        #pragma unroll
        for (int kc = 0; kc < 4; ++kc) {
            acc0 = __builtin_amdgcn_mfma_f32_16x16x32_bf16(afr[0][kc], bfr[kc], acc0, 0, 0, 0);
            acc1 = __builtin_amdgcn_mfma_f32_16x16x32_bf16(afr[1][kc], bfr[kc], acc1, 0, 0, 0);
        }
        float add = bias[col] + (GF ? GF[(size_t)graph * HDIM + col] : 0.f);
        ushort* pl = XD + (size_t)ct * pls;
        #pragma unroll
        for (int r = 0; r < 4; ++r) {
            pl[(r0 + wave * 32 + quad * 4 + r) * 16 + m16] = f2bf(acc0[r] + add);
            pl[(r0 + wave * 32 + 16 + quad * 4 + r) * 16 + m16] = f2bf(acc1[r] + add);
        }
    }
}

// ================= attention prep (both layers): P[l][h*8+t][k] (scale folded in) =================
__global__ __launch_bounds__(256) void attn_prep_kernel(const float* __restrict__ vt,
    const float* __restrict__ qkv_w, const float* __restrict__ qkv_b, float* __restrict__ P)
{
    __shared__ float vtl[TTOK][HDIM];
    __shared__ float q[TTOK][HDIM];
    int l = blockIdx.x;
    const float* vtp = vt + (size_t)l * TTOK * HDIM;
    const float* qw = qkv_w + (size_t)l * 128 * 384;
    const float* qb = qkv_b + (size_t)l * 384;
    float* Pp = P + (size_t)l * 4 * TTOK * HDIM;
    int tid = threadIdx.x;
    for (int i = tid; i < TTOK * HDIM; i += 256) vtl[i >> 7][i & 127] = vtp[i];
    __syncthreads();
    for (int i = tid; i < TTOK * HDIM; i += 256) {
        int t = i >> 7, j = i & 127;
        float acc = qb[j];
        for (int c = 0; c < 128; ++c) acc += vtl[t][c] * qw[c * 384 + j];
        q[t][j] = acc;
    }
    __syncthreads();
    const float scale = 0.17677669529663687f; // 1/sqrt(32)
    for (int i = tid; i < 4 * TTOK * HDIM; i += 256) {
        int h = i >> 10, t = (i >> 7) & 7, cc = i & 127;
        float acc = 0.f;
        for (int d = 0; d < 32; ++d)
            acc += qw[cc * 384 + 128 + h * 32 + d] * q[t][h * 32 + d];
        Pp[i] = acc * scale;
    }
}

// ================= flash-MFMA attention, 4 blocks/graph (2 X-tiles each), plane input =================
__global__ __launch_bounds__(256) void attn_part_kernel(const ushort* __restrict__ X,
    const float* __restrict__ P, float* __restrict__ PART, int pls)
{
    __shared__ ushort Xl[128 * 128];   // 32 KB swizzled X tile
    __shared__ float  St[32 * 132];
    __shared__ ushort Pl[32 * 128];
    __shared__ float lm[32], ll[32], lalpha[32];
    int tid = threadIdx.x;
    int bp = blockIdx.x;
    int b = bp >> 2, part = bp & 3;
    int wave = tid >> 6, lane = tid & 63;
    int m16 = lane & 15, quad = lane >> 4;

    for (int i = tid; i < 2048; i += 256) {
        float2 v = *(const float2*)(P + (size_t)i * 2);
        ((uint*)Pl)[i] = pk(v.x, v.y);
    }
    if (tid < 32) { lm[tid] = -1e30f; ll[tid] = 0.f; }
    __syncthreads();
    short8 aP[2][4];
    #pragma unroll
    for (int mt = 0; mt < 2; ++mt)
        #pragma unroll
        for (int kc = 0; kc < 4; ++kc)
            aP[mt][kc] = *(const short8*)&Pl[(mt * 16 + m16) * 128 + (kc * 4 + quad) * 8];
    __syncthreads();

    f32x4 oacc[2][2] = {};

    for (int t8i = 0; t8i < 2; ++t8i) {
        int t8 = part * 2 + t8i;
        size_t base = (size_t)b * NPG + t8 * 128;
        {
            uint4* xl = (uint4*)Xl;
            for (int i = tid; i < 2048; i += 256) {
                int row = i >> 4, cc = i & 15;
                uint4 v = *(const uint4*)(X + (size_t)(cc >> 1) * pls + (base + row) * 16 + (cc & 1) * 8);
                xl[row * 16 + (cc ^ (row & 15))] = v;
            }
        }
        __syncthreads();
        {
            f32x4 sacc[2][2] = {};
            #pragma unroll
            for (int kc = 0; kc < 4; ++kc) {
                short8 bx[2];
                #pragma unroll
                for (int ntl = 0; ntl < 2; ++ntl) {
                    int node = (2 * wave + ntl) * 16 + m16;
                    bx[ntl] = *(const short8*)&Xl[node * 128 + (((kc * 4 + quad) ^ m16) << 3)];
                }
                #pragma unroll
                for (int mt = 0; mt < 2; ++mt)
                    #pragma unroll
                    for (int ntl = 0; ntl < 2; ++ntl)
                        sacc[mt][ntl] = __builtin_amdgcn_mfma_f32_16x16x32_bf16(
                            aP[mt][kc], bx[ntl], sacc[mt][ntl], 0, 0, 0);
            }
            #pragma unroll
            for (int mt = 0; mt < 2; ++mt)
                #pragma unroll
                for (int ntl = 0; ntl < 2; ++ntl)
                    #pragma unroll
                    for (int r = 0; r < 4; ++r)
                        St[(mt * 16 + quad * 4 + r) * 132 + (2 * wave + ntl) * 16 + m16]
                            = sacc[mt][ntl][r];
        }
        __syncthreads();
        {
            int j = tid >> 3, g = tid & 7;
            const float* rowp = &St[j * 132 + g * 16];
            float4 v0 = *(const float4*)(rowp);
            float4 v1 = *(const float4*)(rowp + 4);
            float4 v2 = *(const float4*)(rowp + 8);
            float4 v3 = *(const float4*)(rowp + 12);
            float mx = fmaxf(fmaxf(fmaxf(v0.x, v0.y), fmaxf(v0.z, v0.w)),
                             fmaxf(fmaxf(v1.x, v1.y), fmaxf(v1.z, v1.w)));
            mx = fmaxf(mx, fmaxf(fmaxf(fmaxf(v2.x, v2.y), fmaxf(v2.z, v2.w)),
                                 fmaxf(fmaxf(v3.x, v3.y), fmaxf(v3.z, v3.w))));
            mx = fmaxf(mx, __shfl_down(mx, 4, 8));
            mx = fmaxf(mx, __shfl_down(mx, 2, 8));
            mx = fmaxf(mx, __shfl_down(mx, 1, 8));
            mx = __shfl(mx, 0, 8);
            float mold = lm[j];
            float Mn = fmaxf(mold, mx);
            float alpha = __expf(mold - Mn);
            float p0 = __expf(v0.x - Mn), p1 = __expf(v0.y - Mn), p2 = __expf(v0.z - Mn), p3 = __expf(v0.w - Mn);
            float p4 = __expf(v1.x - Mn), p5 = __expf(v1.y - Mn), p6 = __expf(v1.z - Mn), p7 = __expf(v1.w - Mn);
            float p8 = __expf(v2.x - Mn), p9 = __expf(v2.y - Mn), pa = __expf(v2.z - Mn), pb = __expf(v2.w - Mn);
            float pc = __expf(v3.x - Mn), pd = __expf(v3.y - Mn), pe = __expf(v3.z - Mn), pf = __expf(v3.w - Mn);
            float s = ((p0 + p1) + (p2 + p3)) + ((p4 + p5) + (p6 + p7))
                    + ((p8 + p9) + (pa + pb)) + ((pc + pd) + (pe + pf));
            s += __shfl_down(s, 4, 8);
            s += __shfl_down(s, 2, 8);
            s += __shfl_down(s, 1, 8);
            if (g == 0) {
                ll[j] = ll[j] * alpha + s;
                lm[j] = Mn;
                lalpha[j] = alpha;
            }
            uint4 u0, u1;
            u0.x = pk(p0, p1); u0.y = pk(p2, p3); u0.z = pk(p4, p5); u0.w = pk(p6, p7);
            u1.x = pk(p8, p9); u1.y = pk(pa, pb); u1.z = pk(pc, pd); u1.w = pk(pe, pf);
            ((uint4*)Pl)[j * 16 + ((2 * g) ^ (j & 15))] = u0;
            ((uint4*)Pl)[j * 16 + ((2 * g + 1) ^ (j & 15))] = u1;
        }
        __syncthreads();
        {
            #pragma unroll
            for (int mt = 0; mt < 2; ++mt)
                #pragma unroll
                for (int r = 0; r < 4; ++r) {
                    float a = lalpha[mt * 16 + quad * 4 + r];
                    oacc[mt][0][r] *= a;
                    oacc[mt][1][r] *= a;
                }
            #pragma unroll
            for (int kc = 0; kc < 4; ++kc) {
                short8 ap2[2], bx[2];
                #pragma unroll
                for (int mt = 0; mt < 2; ++mt)
                    ap2[mt] = *(const short8*)&Pl[(mt * 16 + m16) * 128 + (((kc * 4 + quad) ^ m16) << 3)];
                #pragma unroll
                for (int ntl = 0; ntl < 2; ++ntl) {
                    int cf = (2 * wave + ntl) * 16 + m16;
                    int chi = cf >> 3, clo = cf & 7;
                    short8 v;
                    #pragma unroll
                    for (int jj = 0; jj < 8; ++jj) {
                        int row = kc * 32 + quad * 8 + jj;
                        v[jj] = (short)Xl[(row << 7) + ((chi ^ (row & 15)) << 3) + clo];
                    }
                    bx[ntl] = v;
                }
                #pragma unroll
                for (int mt = 0; mt < 2; ++mt)
                    #pragma unroll
                    for (int ntl = 0; ntl < 2; ++ntl)
                        oacc[mt][ntl] = __builtin_amdgcn_mfma_f32_16x16x32_bf16(
                            ap2[mt], bx[ntl], oacc[mt][ntl], 0, 0, 0);
            }
        }
        __syncthreads();
    }
    float* PB = PART + ((size_t)b * 4 + part) * PARTSZ;
    #pragma unroll
    for (int mt = 0; mt < 2; ++mt)
        #pragma unroll
        for (int r = 0; r < 4; ++r) {
            int j = mt * 16 + quad * 4 + r;
            PB[j * 128 + (2 * wave + 0) * 16 + m16] = oacc[mt][0][r];
            PB[j * 128 + (2 * wave + 1) * 16 + m16] = oacc[mt][1][r];
        }
    if (tid < 32) { PB[4096 + tid] = lm[tid]; PB[4128 + tid] = ll[tid]; }
}

// merge 4 partials + Wv projection + ao projection -> TOK
__global__ __launch_bounds__(256) void attn_merge_kernel(const float* __restrict__ PART,
    const float* __restrict__ qkv_w, const float* __restrict__ qkv_b,
    const float* __restrict__ ao_w, const float* __restrict__ ao_b,
    float* __restrict__ TOK)
{
    __shared__ float R[32 * 132];
    __shared__ float ot[8][128];
    __shared__ float wgt[4][32];
    __shared__ float inv[32];
    int b = blockIdx.x, tid = threadIdx.x;
    const float* PB = PART + (size_t)b * 4 * PARTSZ;
    if (tid < 32) {
        int j = tid;
        float m0 = PB[4096 + j], m1 = PB[PARTSZ + 4096 + j];
        float m2 = PB[2 * PARTSZ + 4096 + j], m3 = PB[3 * PARTSZ + 4096 + j];
        float M = fmaxf(fmaxf(m0, m1), fmaxf(m2, m3));
        float w0 = __expf(m0 - M), w1 = __expf(m1 - M);
        float w2 = __expf(m2 - M), w3 = __expf(m3 - M);
        float L = w0 * PB[4128 + j] + w1 * PB[PARTSZ + 4128 + j]
                + w2 * PB[2 * PARTSZ + 4128 + j] + w3 * PB[3 * PARTSZ + 4128 + j];
        wgt[0][j] = w0; wgt[1][j] = w1; wgt[2][j] = w2; wgt[3][j] = w3;
        inv[j] = 1.f / L;
    }
    __syncthreads();
    for (int idx = tid; idx < 4096; idx += 256) {
        int j = idx >> 7, c = idx & 127;
        float v = wgt[0][j] * PB[idx] + wgt[1][j] * PB[PARTSZ + idx]
                + wgt[2][j] * PB[2 * PARTSZ + idx] + wgt[3][j] * PB[3 * PARTSZ + idx];
        R[j * 132 + c] = v * inv[j];
    }
    __syncthreads();
    for (int idx = tid; idx < 1024; idx += 256) {
        int j = idx >> 5, d = idx & 31;
        int h = j >> 3, t = j & 7;
        int col = 256 + h * 32 + d;
        float acc = qkv_b[col];
        const float* rp = &R[j * 132];
        for (int c = 0; c < 128; ++c) acc += rp[c] * qkv_w[c * 384 + col];
        ot[t][h * 32 + d] = acc;
    }
    __syncthreads();
    for (int idx = tid; idx < 1024; idx += 256) {
        int t = idx >> 7, c = idx & 127;
        float acc = ao_b[c];
        for (int k = 0; k < 128; ++k) acc += ot[t][k] * ao_w[k * 128 + c];
        TOK[((size_t)b * TTOK + t) * HDIM + c] = acc;
    }
}

// ================= mamba: one block per graph; GF[b][:] = mean_t output =================
__global__ __launch_bounds__(256) void mamba_kernel(const float* __restrict__ TOKp,
    const float* __restrict__ in_w, const float* __restrict__ conv_w,
    const float* __restrict__ conv_b, const float* __restrict__ x_w,
    const float* __restrict__ dt_w, const float* __restrict__ dt_b,
    const float* __restrict__ A_log, const float* __restrict__ Dp,
    const float* __restrict__ out_w, const float* __restrict__ norm_w,
    const float* __restrict__ normf_w, float* __restrict__ GF)
{
    constexpr int I = 256, S = 16;
    __shared__ float tok[TTOK][HDIM];
    __shared__ float hn[TTOK][HDIM];
    __shared__ float uu[TTOK][I];
    __shared__ float gg[TTOK][I];
    __shared__ float dtl[TTOK][I];
    __shared__ float ssm[TTOK][40];
    __shared__ float yy[TTOK][I];
    int b = blockIdx.x, tid = threadIdx.x;
    for (int i = tid; i < TTOK * HDIM; i += 256) tok[i >> 7][i & 127] = TOKp[(size_t)b * TTOK * HDIM + i];
    __syncthreads();
    {
        int t = tid >> 5, lane = tid & 31;
        float s = 0.f;
        for (int c = lane; c < HDIM; c += 32) { float v = tok[t][c]; s += v * v; }
        for (int off = 16; off; off >>= 1) s += __shfl_down(s, off, 32);
        s = __shfl(s, 0, 32);
        float r = rsqrtf(s / HDIM + 1e-5f);
        for (int c = lane; c < HDIM; c += 32) hn[t][c] = tok[t][c] * r * norm_w[c];
    }
    __syncthreads();
    for (int it = 0; it < 16; ++it) {
        int idx = it * 256 + tid;
        int t = idx >> 9, j = idx & 511;
        float acc = 0.f;
        for (int c = 0; c < 128; ++c) acc += hn[t][c] * in_w[c * 512 + j];
        if (j < 256) uu[t][j] = acc; else gg[t][j - 256] = acc;
    }
    __syncthreads();
    {
        int i = tid;
        float cw0 = conv_w[i * 4 + 0], cw1 = conv_w[i * 4 + 1];
        float cw2 = conv_w[i * 4 + 2], cw3 = conv_w[i * 4 + 3];
        float cb = conv_b[i];
        float uv[TTOK];
        for (int t = 0; t < TTOK; ++t) uv[t] = uu[t][i];
        for (int t = 0; t < TTOK; ++t) {
            float a = cw3 * uv[t] + cb;
            if (t >= 1) a += cw2 * uv[t - 1];
            if (t >= 2) a += cw1 * uv[t - 2];
            if (t >= 3) a += cw0 * uv[t - 3];
            float sg = 1.f / (1.f + __expf(-a));
            uu[t][i] = a * sg;
        }
    }
    __syncthreads();
    for (int idx = tid; idx < TTOK * 40; idx += 256) {
        int t = idx / 40, j = idx % 40;
        float acc = 0.f;
        for (int c = 0; c < 256; ++c) acc += uu[t][c] * x_w[c * 40 + j];
        ssm[t][j] = acc;
    }
    __syncthreads();
    for (int idx = tid; idx < TTOK * I; idx += 256) {
        int t = idx >> 8, i = idx & 255;
        float acc = dt_b[i];
        for (int r = 0; r < 8; ++r) acc += ssm[t][r] * dt_w[r * 256 + i];
        dtl[t][i] = (acc > 20.f) ? acc : log1pf(__expf(acc));
    }
    __syncthreads();
    {
        int i = tid;
        float a[S], st[S];
        for (int s = 0; s < S; ++s) { a[s] = -__expf(A_log[i * S + s]); st[s] = 0.f; }
        float Di = Dp[i];
        for (int t = 0; t < TTOK; ++t) {
            float d = dtl[t][i];
            float ut = uu[t][i];
            float y = 0.f;
            for (int s = 0; s < S; ++s) {
                float dA = __expf(d * a[s]);
                st[s] = dA * st[s] + d * ssm[t][8 + s] * ut;
                y += st[s] * ssm[t][24 + s];
            }
            y += ut * Di;
            float g = gg[t][i];
            float sg = 1.f / (1.f + __expf(-g));
            yy[t][i] = y * g * sg;
        }
    }
    __syncthreads();
    for (int idx = tid; idx < TTOK * HDIM; idx += 256) {
        int t = idx >> 7, c = idx & 127;
        float acc = tok[t][c];
        for (int i = 0; i < 256; ++i) acc += yy[t][i] * out_w[i * 128 + c];
        hn[t][c] = acc;
    }
    __syncthreads();
    {
        int t = tid >> 5, lane = tid & 31;
        float s = 0.f;
        for (int c = lane; c < HDIM; c += 32) { float v = hn[t][c]; s += v * v; }
        for (int off = 16; off; off >>= 1) s += __shfl_down(s, off, 32);
        s = __shfl(s, 0, 32);
        float r = rsqrtf(s / HDIM + 1e-5f);
        for (int c = lane; c < HDIM; c += 32) hn[t][c] = hn[t][c] * r * normf_w[c];
    }
    __syncthreads();
    for (int c = tid; c < HDIM; c += 256) {
        float s = 0.f;
        for (int t = 0; t < TTOK; ++t) s += hn[t][c];
        GF[(size_t)b * HDIM + c] = s * (1.f / TTOK);
    }
}

// ================= final GIN + segment_sum: sliced partials (slice = blockIdx%8) =================
__global__ __launch_bounds__(256) void final_partial_kernel(const ushort* __restrict__ X,
    const int* __restrict__ ssrc, const int* __restrict__ starts,
    float* __restrict__ PS, int pls)
{
    __shared__ float part[64][16];
    int bp = blockIdx.x;
    int s = bp & 7;
    int gq = bp >> 3;
    int g = gq >> 2, q = gq & 3;
    int tid = threadIdx.x;
    int grp = tid >> 2, lane = tid & 3;
    const ushort* Xp = X + (size_t)s * pls;
    float a0 = 0.f, a1 = 0.f, a2 = 0.f, a3 = 0.f;
    // self rows: 4 per group
    {
        int nb = g * NPG + q * 256 + grp * 4;
        #pragma unroll
        for (int k = 0; k < 4; ++k) {
            uint2 u = *((const uint2*)(Xp + (size_t)(nb + k) * 16) + lane);
            a0 += blo(u.x); a1 += bhi(u.x); a2 += blo(u.y); a3 += bhi(u.y);
        }
    }
    // edge rows: quarter q of graph g's edge range, split over 64 groups
    {
        int e0 = starts[g * NPG], e1 = starts[(g + 1) * NPG];
        int tot = e1 - e0;
        int per = (tot + 3) >> 2;
        int qs = e0 + q * per;
        int qe = min(qs + per, e1);
        int chunk = ((qe - qs) + 63) >> 6;
        int cs = qs + grp * chunk;
        int ce = min(cs + chunk, qe);
        for (int j0 = cs; j0 < ce; j0 += 4) {
            int myid = (j0 + lane < ce) ? ssrc[j0 + lane] : 0;
            int m = ce - j0;
            if (m >= 4) {
                int i0 = __shfl(myid, 0, 4), i1 = __shfl(myid, 1, 4);
                int i2 = __shfl(myid, 2, 4), i3 = __shfl(myid, 3, 4);
                uint2 u0 = *((const uint2*)(Xp + (size_t)i0 * 16) + lane);
                uint2 u1 = *((const uint2*)(Xp + (size_t)i1 * 16) + lane);
                uint2 u2 = *((const uint2*)(Xp + (size_t)i2 * 16) + lane);
                uint2 u3 = *((const uint2*)(Xp + (size_t)i3 * 16) + lane);
                a0 += (blo(u0.x) + blo(u1.x)) + (blo(u2.x) + blo(u3.x));
                a1 += (bhi(u0.x) + bhi(u1.x)) + (bhi(u2.x) + bhi(u3.x));
                a2 += (blo(u0.y) + blo(u1.y)) + (blo(u2.y) + blo(u3.y));
                a3 += (bhi(u0.y) + bhi(u1.y)) + (bhi(u2.y) + bhi(u3.y));
            } else {
                for (int j = 0; j < m; ++j) {
                    int ii = __shfl(myid, j, 4);
                    uint2 u = *((const uint2*)(Xp + (size_t)ii * 16) + lane);
                    a0 += blo(u.x); a1 += bhi(u.x); a2 += blo(u.y); a3 += bhi(u.y);
                }
            }
        }
    }
    part[grp][lane * 4 + 0] = a0; part[grp][lane * 4 + 1] = a1;
    part[grp][lane * 4 + 2] = a2; part[grp][lane * 4 + 3] = a3;
    __syncthreads();
    if (tid < 16) {
        float sum = 0.f;
        for (int gg = 0; gg < 64; ++gg) sum += part[gg][tid];
        atomicAdd(&PS[(size_t)g * HDIM + s * 16 + tid], sum);
    }
}

__global__ __launch_bounds__(128) void final_mm_kernel(const float* __restrict__ PS,
    const float* __restrict__ w_out, const float* __restrict__ b_out,
    float* __restrict__ out)
{
    __shared__ float Sm[HDIM];
    int b = blockIdx.x, tid = threadIdx.x;
    Sm[tid] = PS[(size_t)b * HDIM + tid];
    __syncthreads();
    float acc = 1024.f * b_out[tid];
    for (int k = 0; k < 128; ++k) acc += Sm[k] * w_out[k * 128 + tid];
    out[(size_t)b * HDIM + tid] = acc;
}

extern "C" void kernel_launch(void* const* d_in, const int* in_sizes, int n_in,
                              void* d_out, int out_size, void* d_ws, size_t ws_size,
                              hipStream_t stream)
{
    const int N = in_sizes[0] / HDIM;      // 131072
    const int E = in_sizes[1] / 2;         // 2097152
    const int B = N >> 10;                 // 128 graphs
    const int PLS = N * 16;                // plane stride (ushorts) = 4 MiB

    const float* x_in  = (const float*)d_in[0];
    const int*   src   = (const int*)d_in[1];
    const int*   dst   = src + E;
    const float* w_in  = (const float*)d_in[5];
    const float* b_in  = (const float*)d_in[6];
    const float* gin_w = (const float*)d_in[7];
    const float* gin_b = (const float*)d_in[8];
    const float* vt    = (const float*)d_in[9];
    const float* qkv_w = (const float*)d_in[10];
    const float* qkv_b = (const float*)d_in[11];
    const float* ao_w  = (const float*)d_in[12];
    const float* ao_b  = (const float*)d_in[13];
    const float* m_in_w   = (const float*)d_in[14];
    const float* m_conv_w = (const float*)d_in[15];
    const float* m_conv_b = (const float*)d_in[16];
    const float* m_x_w    = (const float*)d_in[17];
    const float* m_dt_w   = (const float*)d_in[18];
    const float* m_dt_b   = (const float*)d_in[19];
    const float* m_A_log  = (const float*)d_in[20];
    const float* m_D      = (const float*)d_in[21];
    const float* m_out_w  = (const float*)d_in[22];
    const float* m_norm_w = (const float*)d_in[23];
    const float* m_normf_w= (const float*)d_in[24];
    const float* w_out = (const float*)d_in[25];
    const float* b_out = (const float*)d_in[26];
    float* out = (float*)d_out;

    float* TOK = (float*)d_ws;                        // B*8*128
    float* GF  = TOK + (size_t)B * TTOK * HDIM;       // B*128
    float* P   = GF + (size_t)B * HDIM;               // 2*4*8*128
    float* PART= P + 2 * 4 * TTOK * HDIM;             // B*4*PARTSZ
    int* bcursor = (int*)(PART + (size_t)B * 4 * PARTSZ);  // 512
    float* PS  = (float*)(bcursor + NBUCK);           // B*128 (adjacent -> one memset)
    uint* pairbuf = (uint*)(PS + (size_t)B * HDIM);   // NBUCK*BCAP uints
    int* count    = (int*)(pairbuf + (size_t)NBUCK * BCAP);  // N
    int* starts   = count + N;                        // N+1 (padded to N+8)
    int* ssrc     = starts + N + 8;                   // E
    ushort* XB0 = (ushort*)(ssrc + E);                // N*128 bf16 (8 planes)
    ushort* XB1 = XB0 + (size_t)N * HDIM;             // N*128 bf16 (8 planes)
    ushort* AGG = XB1 + (size_t)N * HDIM;             // N*128 bf16 (8 planes)

    // ---- binned sort of edges by dst (once, reused by all 4 GINs) ----
    hipMemsetAsync(bcursor, 0, NBUCK * sizeof(int) + (size_t)B * HDIM * sizeof(float), stream);
    bin_kernel<<<(E + EPB - 1) / EPB, 256, 0, stream>>>(src, dst, bcursor, pairbuf, E);
    bucket_sort_kernel<<<NBUCK, 256, 0, stream>>>(pairbuf, bcursor, ssrc, starts, count, N);

    // ---- attention prep for both layers (independent of X) ----
    attn_prep_kernel<<<2, 256, 0, stream>>>(vt, qkv_w, qkv_b, P);

    // ---- input GIN: XB1 = (x + agg(x)) @ w_in + b_in ----
    convert_kernel<<<(N * 16 + 255) / 256, 256, 0, stream>>>(x_in, XB0, N * 16, PLS);
    gather_kernel<<<(N / 64) * 8, 256, 0, stream>>>(XB0, ssrc, starts, count, AGG, PLS);
    lin128_mfma_kernel<<<N / 128, 256, 0, stream>>>(AGG, w_in, b_in, nullptr, XB1, PLS);

    ushort* Xcur = XB1;
    ushort* Xnext = XB0;
    for (int l = 0; l < 2; ++l) {
        // attention pool: 4 partial blocks/graph, then merge (+Wv +ao) -> TOK
        attn_part_kernel<<<B * 4, 256, 0, stream>>>(Xcur, P + (size_t)l * 4 * TTOK * HDIM, PART, PLS);
        attn_merge_kernel<<<B, 256, 0, stream>>>(PART,
                                                 qkv_w + (size_t)l * 128 * 384,
                                                 qkv_b + (size_t)l * 384,
                                                 ao_w + (size_t)l * 128 * 128,
                                                 ao_b + (size_t)l * 128, TOK);
        mamba_kernel<<<B, 256, 0, stream>>>(TOK, m_in_w, m_conv_w, m_conv_b, m_x_w,
                                            m_dt_w, m_dt_b, m_A_log, m_D, m_out_w,
                                            m_norm_w, m_normf_w, GF);
        // GIN: AGG = Xcur + agg(Xcur); Xnext = AGG @ gin_w + gin_b + GF[batch]
        gather_kernel<<<(N / 64) * 8, 256, 0, stream>>>(Xcur, ssrc, starts, count, AGG, PLS);
        lin128_mfma_kernel<<<N / 128, 256, 0, stream>>>(AGG, gin_w + (size_t)l * 128 * 128,
                                                        gin_b + (size_t)l * 128, GF, Xnext, PLS);
        ushort* t = Xcur; Xcur = Xnext; Xnext = t;
    }

    // ---- final GIN + segment_sum: sliced partials + tiny matmul ----
    final_partial_kernel<<<B * 32, 256, 0, stream>>>(Xcur, ssrc, starts, PS, PLS);
    final_mm_kernel<<<B, 128, 0, stream>>>(PS, w_out, b_out, out);

    (void)n_in; (void)out_size; (void)ws_size;
}

// Round 12
// 998.000 us; speedup vs baseline: 1.1157x; 1.1157x over previous
//
#include <hip/hip_runtime.h>

#define HDIM 128
#define TTOK 8
#define NPG 1024
#define NBUCK 512
#define BSHIFT 8
#define BCAP 6144
#define EPB 4096
#define PARTSZ 4160   // per (graph,part): 32*128 O + 32 m + 32 l

typedef unsigned short ushort;
typedef unsigned int uint;
typedef __attribute__((ext_vector_type(8))) short short8;
typedef __attribute__((ext_vector_type(4))) float f32x4;

__device__ __forceinline__ float bf2f(ushort u) {
    return __uint_as_float(((unsigned int)u) << 16);
}
__device__ __forceinline__ ushort f2bf(float f) {
    unsigned int x = __float_as_uint(f);
    return (ushort)((x + 0x7FFFu + ((x >> 16) & 1u)) >> 16);
}
__device__ __forceinline__ float blo(uint u) { return __uint_as_float(u << 16); }
__device__ __forceinline__ float bhi(uint u) { return __uint_as_float(u & 0xFFFF0000u); }
__device__ __forceinline__ uint pk(float a, float b) {
    return (uint)f2bf(a) | ((uint)f2bf(b) << 16);
}

// ================= binned sort of edges by dst =================
__global__ __launch_bounds__(256) void bin_kernel(const int* __restrict__ src,
    const int* __restrict__ dst, int* __restrict__ bcursor,
    uint* __restrict__ pairbuf, int E)
{
    __shared__ int lcnt[NBUCK];
    __shared__ int lbase[NBUCK];
    int tid = threadIdx.x;
    int e0 = blockIdx.x * EPB;
    for (int i = tid; i < NBUCK; i += 256) lcnt[i] = 0;
    __syncthreads();
    uint pkd[16];
    int bk[16], rk[16];
    #pragma unroll
    for (int i = 0; i < 16; ++i) {
        int e = e0 + i * 256 + tid;
        int s = (e < E) ? src[e] : 0;
        int d = (e < E) ? dst[e] : -1;
        int b = d >> BSHIFT;
        bk[i] = b;
        pkd[i] = ((uint)(d & 255) << 17) | (uint)s;
        rk[i] = (e < E) ? atomicAdd(&lcnt[b], 1) : 0;
    }
    __syncthreads();
    for (int i = tid; i < NBUCK; i += 256) {
        int c = lcnt[i];
        lbase[i] = c ? atomicAdd(&bcursor[i], c) : 0;
    }
    __syncthreads();
    #pragma unroll
    for (int i = 0; i < 16; ++i) {
        if (bk[i] >= 0) {
            int slot = lbase[bk[i]] + rk[i];
            if (slot < BCAP) pairbuf[(size_t)bk[i] * BCAP + slot] = pkd[i];
        }
    }
}

// Pass B: one block per bucket; self-scans bucket counts.
__global__ __launch_bounds__(256) void bucket_sort_kernel(const uint* __restrict__ pairbuf,
    const int* __restrict__ bcount,
    int* __restrict__ ssrc, int* __restrict__ starts, int* __restrict__ countn, int N)
{
    __shared__ int sc[NBUCK];
    __shared__ int lcount[256];
    __shared__ int lcur[256];
    __shared__ int lss[BCAP];   // 24 KB
    int b = blockIdx.x;
    int tid = threadIdx.x;
    sc[tid] = min(bcount[tid], BCAP);
    sc[tid + 256] = min(bcount[tid + 256], BCAP);
    lcount[tid] = 0;
    __syncthreads();
    for (int off = 1; off < NBUCK; off <<= 1) {
        int a0 = (tid >= off) ? sc[tid - off] : 0;
        int a1 = (tid + 256 >= off) ? sc[tid + 256 - off] : 0;
        __syncthreads();
        sc[tid] += a0; sc[tid + 256] += a1;
        __syncthreads();
    }
    int nb = min(bcount[b], BCAP);
    int base = sc[b] - nb;
    const uint* pp = pairbuf + (size_t)b * BCAP;
    for (int i = tid; i < nb; i += 256)
        atomicAdd(&lcount[(pp[i] >> 17) & 255], 1);
    __syncthreads();
    int v = lcount[tid];
    lcur[tid] = v;
    __syncthreads();
    for (int off = 1; off < 256; off <<= 1) {
        int t = (tid >= off) ? lcur[tid - off] : 0;
        __syncthreads();
        lcur[tid] += t;
        __syncthreads();
    }
    int excl = lcur[tid] - v;
    int node = b * 256 + tid;
    starts[node] = base + excl;
    countn[node] = v;
    __syncthreads();
    lcur[tid] = excl;
    __syncthreads();
    for (int i = tid; i < nb; i += 256) {
        uint p = pp[i];
        int pos = atomicAdd(&lcur[(p >> 17) & 255], 1);
        lss[pos] = (int)(p & 0x1FFFFu);
    }
    __syncthreads();
    for (int i = tid; i < nb; i += 256) ssrc[base + i] = lss[i];
    if (b == NBUCK - 1 && tid == 0) starts[N] = base + nb;
}

// ================= f32 -> bf16 convert =================
__global__ __launch_bounds__(256) void convert_kernel(const float* __restrict__ in,
                                                      ushort* __restrict__ outb, int n4)
{
    int i = blockIdx.x * 256 + threadIdx.x;
    if (i >= n4) return;
    float4 v = ((const float4*)in)[i];
    uint2 o;
    o.x = pk(v.x, v.y); o.y = pk(v.z, v.w);
    ((uint2*)outb)[i] = o;
}

// ================= gather: AGG[n] = x[n] + sum_{e: dst=n} x[src[e]]  (bf16, 8-deep ILP) =================
__global__ __launch_bounds__(256) void gather_kernel(const ushort* __restrict__ XS,
    const int* __restrict__ ssrc, const int* __restrict__ starts,
    const int* __restrict__ count, ushort* __restrict__ AGG)
{
    int tid = threadIdx.x;
    int g = tid >> 4, lane = tid & 15;
    int node = blockIdx.x * 16 + g;
    uint4 sv = *((const uint4*)(XS + (size_t)node * HDIM) + lane);
    float a0 = blo(sv.x), a1 = bhi(sv.x), a2 = blo(sv.y), a3 = bhi(sv.y);
    float a4 = blo(sv.z), a5 = bhi(sv.z), a6 = blo(sv.w), a7 = bhi(sv.w);
    int s0 = starts[node], cn = count[node];
    for (int j0 = 0; j0 < cn; j0 += 16) {
        int myid = (j0 + lane < cn) ? ssrc[s0 + j0 + lane] : 0;
        int m = min(16, cn - j0);
        int j = 0;
        for (; j + 7 < m; j += 8) {
            uint4 u[8];
            #pragma unroll
            for (int q = 0; q < 8; ++q) {
                int sidx = __shfl(myid, j + q, 16);
                u[q] = *((const uint4*)(XS + (size_t)sidx * HDIM) + lane);
            }
            #pragma unroll
            for (int q = 0; q < 8; ++q) {
                a0 += blo(u[q].x); a1 += bhi(u[q].x);
                a2 += blo(u[q].y); a3 += bhi(u[q].y);
                a4 += blo(u[q].z); a5 += bhi(u[q].z);
                a6 += blo(u[q].w); a7 += bhi(u[q].w);
            }
        }
        for (; j + 3 < m; j += 4) {
            uint4 u[4];
            #pragma unroll
            for (int q = 0; q < 4; ++q) {
                int sidx = __shfl(myid, j + q, 16);
                u[q] = *((const uint4*)(XS + (size_t)sidx * HDIM) + lane);
            }
            #pragma unroll
            for (int q = 0; q < 4; ++q) {
                a0 += blo(u[q].x); a1 += bhi(u[q].x);
                a2 += blo(u[q].y); a3 += bhi(u[q].y);
                a4 += blo(u[q].z); a5 += bhi(u[q].z);
                a6 += blo(u[q].w); a7 += bhi(u[q].w);
            }
        }
        for (; j < m; ++j) {
            int sidx = __shfl(myid, j, 16);
            uint4 ua = *((const uint4*)(XS + (size_t)sidx * HDIM) + lane);
            a0 += blo(ua.x); a1 += bhi(ua.x);
            a2 += blo(ua.y); a3 += bhi(ua.y);
            a4 += blo(ua.z); a5 += bhi(ua.z);
            a6 += blo(ua.w); a7 += bhi(ua.w);
        }
    }
    uint4 o;
    o.x = pk(a0, a1); o.y = pk(a2, a3); o.z = pk(a4, a5); o.w = pk(a6, a7);
    *((uint4*)(AGG + (size_t)node * HDIM) + lane) = o;
}

// ================= MFMA linear (bf16 in/out): XD = XS @ W + b [+ GF[row>>10]] =================
__global__ __launch_bounds__(256) void lin128_mfma_kernel(const ushort* __restrict__ XS,
    const float* __restrict__ W, const float* __restrict__ bias,
    const float* __restrict__ GF, ushort* __restrict__ XD)
{
    __shared__ ushort Xl[128 * 128];
    __shared__ ushort Wl[128 * 128];
    int tid = threadIdx.x;
    size_t r0 = (size_t)blockIdx.x * 128;
    {
        const uint4* xs = (const uint4*)(XS + r0 * HDIM);
        uint4* xl = (uint4*)Xl;
        for (int i = tid; i < 2048; i += 256) {
            int row = i >> 4, cc = i & 15;
            xl[row * 16 + (cc ^ (row & 15))] = xs[i];
        }
    }
    {
        uint4* wl = (uint4*)Wl;
        for (int i = tid; i < 2048; i += 256) {
            int n = i & 127, c = i >> 7;
            const float* wp = W + (size_t)(c * 8) * 128 + n;
            float w0 = wp[0], w1 = wp[128], w2 = wp[256], w3 = wp[384];
            float w4 = wp[512], w5 = wp[640], w6 = wp[768], w7 = wp[896];
            uint4 u;
            u.x = pk(w0, w1); u.y = pk(w2, w3); u.z = pk(w4, w5); u.w = pk(w6, w7);
            wl[n * 16 + (c ^ (n & 15))] = u;
        }
    }
    __syncthreads();
    int wave = tid >> 6;
    int lane = tid & 63;
    int m16 = lane & 15, quad = lane >> 4;
    const short8* Xf = (const short8*)Xl;
    const short8* Wf = (const short8*)Wl;
    short8 afr[2][4];
    #pragma unroll
    for (int rt = 0; rt < 2; ++rt)
        #pragma unroll
        for (int kc = 0; kc < 4; ++kc)
            afr[rt][kc] = Xf[(wave * 32 + rt * 16 + m16) * 16 + ((kc * 4 + quad) ^ m16)];
    int graph = (int)(r0 >> 10);
    #pragma unroll
    for (int ct = 0; ct < 8; ++ct) {
        int col = ct * 16 + m16;
        short8 bfr[4];
        #pragma unroll
        for (int kc = 0; kc < 4; ++kc)
            bfr[kc] = Wf[col * 16 + ((kc * 4 + quad) ^ m16)];
        f32x4 acc0 = {0.f, 0.f, 0.f, 0.f};
        f32x4 acc1 = {0.f, 0.f, 0.f, 0.f};
        #pragma unroll
        for (int kc = 0; kc < 4; ++kc) {
            acc0 = __builtin_amdgcn_mfma_f32_16x16x32_bf16(afr[0][kc], bfr[kc], acc0, 0, 0, 0);
            acc1 = __builtin_amdgcn_mfma_f32_16x16x32_bf16(afr[1][kc], bfr[kc], acc1, 0, 0, 0);
        }
        float add = bias[col] + (GF ? GF[(size_t)graph * HDIM + col] : 0.f);
        #pragma unroll
        for (int r = 0; r < 4; ++r) {
            XD[(r0 + wave * 32 + quad * 4 + r) * HDIM + col] = f2bf(acc0[r] + add);
            XD[(r0 + wave * 32 + 16 + quad * 4 + r) * HDIM + col] = f2bf(acc1[r] + add);
        }
    }
}

// ================= attention prep (both layers): P[l][h*8+t][k] (scale folded in) =================
__global__ __launch_bounds__(256) void attn_prep_kernel(const float* __restrict__ vt,
    const float* __restrict__ qkv_w, const float* __restrict__ qkv_b, float* __restrict__ P)
{
    __shared__ float vtl[TTOK][HDIM];
    __shared__ float q[TTOK][HDIM];
    int l = blockIdx.x;
    const float* vtp = vt + (size_t)l * TTOK * HDIM;
    const float* qw = qkv_w + (size_t)l * 128 * 384;
    const float* qb = qkv_b + (size_t)l * 384;
    float* Pp = P + (size_t)l * 4 * TTOK * HDIM;
    int tid = threadIdx.x;
    for (int i = tid; i < TTOK * HDIM; i += 256) vtl[i >> 7][i & 127] = vtp[i];
    __syncthreads();
    for (int i = tid; i < TTOK * HDIM; i += 256) {
        int t = i >> 7, j = i & 127;
        float acc = qb[j];
        for (int c = 0; c < 128; ++c) acc += vtl[t][c] * qw[c * 384 + j];
        q[t][j] = acc;
    }
    __syncthreads();
    const float scale = 0.17677669529663687f; // 1/sqrt(32)
    for (int i = tid; i < 4 * TTOK * HDIM; i += 256) {
        int h = i >> 10, t = (i >> 7) & 7, cc = i & 127;
        float acc = 0.f;
        for (int d = 0; d < 32; ++d)
            acc += qw[cc * 384 + 128 + h * 32 + d] * q[t][h * 32 + d];
        Pp[i] = acc * scale;
    }
}

// ================= flash-MFMA attention, 4 blocks/graph (2 X-tiles each) =================
__global__ __launch_bounds__(256) void attn_part_kernel(const ushort* __restrict__ X,
    const float* __restrict__ P, float* __restrict__ PART)
{
    __shared__ ushort Xl[128 * 128];   // 32 KB swizzled X tile
    __shared__ float  St[32 * 132];
    __shared__ ushort Pl[32 * 128];
    __shared__ float lm[32], ll[32], lalpha[32];
    int tid = threadIdx.x;
    int bp = blockIdx.x;
    int b = bp >> 2, part = bp & 3;
    int wave = tid >> 6, lane = tid & 63;
    int m16 = lane & 15, quad = lane >> 4;

    for (int i = tid; i < 2048; i += 256) {
        float2 v = *(const float2*)(P + (size_t)i * 2);
        ((uint*)Pl)[i] = pk(v.x, v.y);
    }
    if (tid < 32) { lm[tid] = -1e30f; ll[tid] = 0.f; }
    __syncthreads();
    short8 aP[2][4];
    #pragma unroll
    for (int mt = 0; mt < 2; ++mt)
        #pragma unroll
        for (int kc = 0; kc < 4; ++kc)
            aP[mt][kc] = *(const short8*)&Pl[(mt * 16 + m16) * 128 + (kc * 4 + quad) * 8];
    __syncthreads();

    f32x4 oacc[2][2] = {};
    const uint4* xsg = (const uint4*)(X + (size_t)b * NPG * HDIM);

    for (int t8i = 0; t8i < 2; ++t8i) {
        int t8 = part * 2 + t8i;
        {
            const uint4* xs = xsg + t8 * 2048;
            uint4* xl = (uint4*)Xl;
            for (int i = tid; i < 2048; i += 256) {
                int row = i >> 4, cc = i & 15;
                xl[row * 16 + (cc ^ (row & 15))] = xs[i];
            }
        }
        __syncthreads();
        {
            f32x4 sacc[2][2] = {};
            #pragma unroll
            for (int kc = 0; kc < 4; ++kc) {
                short8 bx[2];
                #pragma unroll
                for (int ntl = 0; ntl < 2; ++ntl) {
                    int node = (2 * wave + ntl) * 16 + m16;
                    bx[ntl] = *(const short8*)&Xl[node * 128 + (((kc * 4 + quad) ^ m16) << 3)];
                }
                #pragma unroll
                for (int mt = 0; mt < 2; ++mt)
                    #pragma unroll
                    for (int ntl = 0; ntl < 2; ++ntl)
                        sacc[mt][ntl] = __builtin_amdgcn_mfma_f32_16x16x32_bf16(
                            aP[mt][kc], bx[ntl], sacc[mt][ntl], 0, 0, 0);
            }
            #pragma unroll
            for (int mt = 0; mt < 2; ++mt)
                #pragma unroll
                for (int ntl = 0; ntl < 2; ++ntl)
                    #pragma unroll
                    for (int r = 0; r < 4; ++r)
                        St[(mt * 16 + quad * 4 + r) * 132 + (2 * wave + ntl) * 16 + m16]
                            = sacc[mt][ntl][r];
        }
        __syncthreads();
        {
            int j = tid >> 3, g = tid & 7;
            const float* rowp = &St[j * 132 + g * 16];
            float4 v0 = *(const float4*)(rowp);
            float4 v1 = *(const float4*)(rowp + 4);
            float4 v2 = *(const float4*)(rowp + 8);
            float4 v3 = *(const float4*)(rowp + 12);
            float mx = fmaxf(fmaxf(fmaxf(v0.x, v0.y), fmaxf(v0.z, v0.w)),
                             fmaxf(fmaxf(v1.x, v1.y), fmaxf(v1.z, v1.w)));
            mx = fmaxf(mx, fmaxf(fmaxf(fmaxf(v2.x, v2.y), fmaxf(v2.z, v2.w)),
                                 fmaxf(fmaxf(v3.x, v3.y), fmaxf(v3.z, v3.w))));
            mx = fmaxf(mx, __shfl_down(mx, 4, 8));
            mx = fmaxf(mx, __shfl_down(mx, 2, 8));
            mx = fmaxf(mx, __shfl_down(mx, 1, 8));
            mx = __shfl(mx, 0, 8);
            float mold = lm[j];
            float Mn = fmaxf(mold, mx);
            float alpha = __expf(mold - Mn);
            float p0 = __expf(v0.x - Mn), p1 = __expf(v0.y - Mn), p2 = __expf(v0.z - Mn), p3 = __expf(v0.w - Mn);
            float p4 = __expf(v1.x - Mn), p5 = __expf(v1.y - Mn), p6 = __expf(v1.z - Mn), p7 = __expf(v1.w - Mn);
            float p8 = __expf(v2.x - Mn), p9 = __expf(v2.y - Mn), pa = __expf(v2.z - Mn), pb = __expf(v2.w - Mn);
            float pc = __expf(v3.x - Mn), pd = __expf(v3.y - Mn), pe = __expf(v3.z - Mn), pf = __expf(v3.w - Mn);
            float s = ((p0 + p1) + (p2 + p3)) + ((p4 + p5) + (p6 + p7))
                    + ((p8 + p9) + (pa + pb)) + ((pc + pd) + (pe + pf));
            s += __shfl_down(s, 4, 8);
            s += __shfl_down(s, 2, 8);
            s += __shfl_down(s, 1, 8);
            if (g == 0) {
                ll[j] = ll[j] * alpha + s;
                lm[j] = Mn;
                lalpha[j] = alpha;
            }
            uint4 u0, u1;
            u0.x = pk(p0, p1); u0.y = pk(p2, p3); u0.z = pk(p4, p5); u0.w = pk(p6, p7);
            u1.x = pk(p8, p9); u1.y = pk(pa, pb); u1.z = pk(pc, pd); u1.w = pk(pe, pf);
            ((uint4*)Pl)[j * 16 + ((2 * g) ^ (j & 15))] = u0;
            ((uint4*)Pl)[j * 16 + ((2 * g + 1) ^ (j & 15))] = u1;
        }
        __syncthreads();
        {
            #pragma unroll
            for (int mt = 0; mt < 2; ++mt)
                #pragma unroll
                for (int r = 0; r < 4; ++r) {
                    float a = lalpha[mt * 16 + quad * 4 + r];
                    oacc[mt][0][r] *= a;
                    oacc[mt][1][r] *= a;
                }
            #pragma unroll
            for (int kc = 0; kc < 4; ++kc) {
                short8 ap2[2], bx[2];
                #pragma unroll
                for (int mt = 0; mt < 2; ++mt)
                    ap2[mt] = *(const short8*)&Pl[(mt * 16 + m16) * 128 + (((kc * 4 + quad) ^ m16) << 3)];
                #pragma unroll
                for (int ntl = 0; ntl < 2; ++ntl) {
                    int cf = (2 * wave + ntl) * 16 + m16;
                    int chi = cf >> 3, clo = cf & 7;
                    short8 v;
                    #pragma unroll
                    for (int jj = 0; jj < 8; ++jj) {
                        int row = kc * 32 + quad * 8 + jj;
                        v[jj] = (short)Xl[(row << 7) + ((chi ^ (row & 15)) << 3) + clo];
                    }
                    bx[ntl] = v;
                }
                #pragma unroll
                for (int mt = 0; mt < 2; ++mt)
                    #pragma unroll
                    for (int ntl = 0; ntl < 2; ++ntl)
                        oacc[mt][ntl] = __builtin_amdgcn_mfma_f32_16x16x32_bf16(
                            ap2[mt], bx[ntl], oacc[mt][ntl], 0, 0, 0);
            }
        }
        __syncthreads();
    }
    float* PB = PART + ((size_t)b * 4 + part) * PARTSZ;
    #pragma unroll
    for (int mt = 0; mt < 2; ++mt)
        #pragma unroll
        for (int r = 0; r < 4; ++r) {
            int j = mt * 16 + quad * 4 + r;
            PB[j * 128 + (2 * wave + 0) * 16 + m16] = oacc[mt][0][r];
            PB[j * 128 + (2 * wave + 1) * 16 + m16] = oacc[mt][1][r];
        }
    if (tid < 32) { PB[4096 + tid] = lm[tid]; PB[4128 + tid] = ll[tid]; }
}

// ================= mamba (with fused attn-merge front): one block per graph =================
__global__ __launch_bounds__(256) void mamba_kernel(const float* __restrict__ PART,
    const float* __restrict__ qkv_w, const float* __restrict__ qkv_b,
    const float* __restrict__ ao_w, const float* __restrict__ ao_b,
    const float* __restrict__ in_w, const float* __restrict__ conv_w,
    const float* __restrict__ conv_b, const float* __restrict__ x_w,
    const float* __restrict__ dt_w, const float* __restrict__ dt_b,
    const float* __restrict__ A_log, const float* __restrict__ Dp,
    const float* __restrict__ out_w, const float* __restrict__ norm_w,
    const float* __restrict__ normf_w, float* __restrict__ GF)
{
    constexpr int I = 256, S = 16;
    __shared__ float R[32 * 132];
    __shared__ float wgt[4][32];
    __shared__ float inv[32];
    __shared__ float tok[TTOK][HDIM];
    __shared__ float hn[TTOK][HDIM];
    __shared__ float uu[TTOK][I];
    __shared__ float gg[TTOK][I];
    __shared__ float dtl[TTOK][I];
    __shared__ float ssm[TTOK][40];
    __shared__ float yy[TTOK][I];
    int b = blockIdx.x, tid = threadIdx.x;

    // ---- fused attention merge: PART -> R -> (Wv) -> ot -> (ao) -> tok ----
    const float* PB = PART + (size_t)b * 4 * PARTSZ;
    if (tid < 32) {
        int j = tid;
        float m0 = PB[4096 + j], m1 = PB[PARTSZ + 4096 + j];
        float m2 = PB[2 * PARTSZ + 4096 + j], m3 = PB[3 * PARTSZ + 4096 + j];
        float M = fmaxf(fmaxf(m0, m1), fmaxf(m2, m3));
        float w0 = __expf(m0 - M), w1 = __expf(m1 - M);
        float w2 = __expf(m2 - M), w3 = __expf(m3 - M);
        float L = w0 * PB[4128 + j] + w1 * PB[PARTSZ + 4128 + j]
                + w2 * PB[2 * PARTSZ + 4128 + j] + w3 * PB[3 * PARTSZ + 4128 + j];
        wgt[0][j] = w0; wgt[1][j] = w1; wgt[2][j] = w2; wgt[3][j] = w3;
        inv[j] = 1.f / L;
    }
    __syncthreads();
    for (int idx = tid; idx < 4096; idx += 256) {
        int j = idx >> 7, c = idx & 127;
        float v = wgt[0][j] * PB[idx] + wgt[1][j] * PB[PARTSZ + idx]
                + wgt[2][j] * PB[2 * PARTSZ + idx] + wgt[3][j] * PB[3 * PARTSZ + idx];
        R[j * 132 + c] = v * inv[j];
    }
    __syncthreads();
    // Wv projection into hn (used as temp ot): hn[t][h*32+d]
    for (int idx = tid; idx < 1024; idx += 256) {
        int j = idx >> 5, d = idx & 31;
        int h = j >> 3, t = j & 7;
        int col = 256 + h * 32 + d;
        float acc = qkv_b[col];
        const float* rp = &R[j * 132];
        for (int c = 0; c < 128; ++c) acc += rp[c] * qkv_w[c * 384 + col];
        hn[t][h * 32 + d] = acc;
    }
    __syncthreads();
    // ao projection -> tok
    for (int idx = tid; idx < 1024; idx += 256) {
        int t = idx >> 7, c = idx & 127;
        float acc = ao_b[c];
        for (int k = 0; k < 128; ++k) acc += hn[t][k] * ao_w[k * 128 + c];
        tok[t][c] = acc;
    }
    __syncthreads();

    // ---- mamba proper ----
    {
        int t = tid >> 5, lane = tid & 31;
        float s = 0.f;
        for (int c = lane; c < HDIM; c += 32) { float v = tok[t][c]; s += v * v; }
        for (int off = 16; off; off >>= 1) s += __shfl_down(s, off, 32);
        s = __shfl(s, 0, 32);
        float r = rsqrtf(s / HDIM + 1e-5f);
        for (int c = lane; c < HDIM; c += 32) hn[t][c] = tok[t][c] * r * norm_w[c];
    }
    __syncthreads();
    for (int it = 0; it < 16; ++it) {
        int idx = it * 256 + tid;
        int t = idx >> 9, j = idx & 511;
        float acc = 0.f;
        for (int c = 0; c < 128; ++c) acc += hn[t][c] * in_w[c * 512 + j];
        if (j < 256) uu[t][j] = acc; else gg[t][j - 256] = acc;
    }
    __syncthreads();
    {
        int i = tid;
        float cw0 = conv_w[i * 4 + 0], cw1 = conv_w[i * 4 + 1];
        float cw2 = conv_w[i * 4 + 2], cw3 = conv_w[i * 4 + 3];
        float cb = conv_b[i];
        float uv[TTOK];
        for (int t = 0; t < TTOK; ++t) uv[t] = uu[t][i];
        for (int t = 0; t < TTOK; ++t) {
            float a = cw3 * uv[t] + cb;
            if (t >= 1) a += cw2 * uv[t - 1];
            if (t >= 2) a += cw1 * uv[t - 2];
            if (t >= 3) a += cw0 * uv[t - 3];
            float sg = 1.f / (1.f + __expf(-a));
            uu[t][i] = a * sg;
        }
    }
    __syncthreads();
    for (int idx = tid; idx < TTOK * 40; idx += 256) {
        int t = idx / 40, j = idx % 40;
        float acc = 0.f;
        for (int c = 0; c < 256; ++c) acc += uu[t][c] * x_w[c * 40 + j];
        ssm[t][j] = acc;
    }
    __syncthreads();
    for (int idx = tid; idx < TTOK * I; idx += 256) {
        int t = idx >> 8, i = idx & 255;
        float acc = dt_b[i];
        for (int r = 0; r < 8; ++r) acc += ssm[t][r] * dt_w[r * 256 + i];
        dtl[t][i] = (acc > 20.f) ? acc : log1pf(__expf(acc));
    }
    __syncthreads();
    {
        int i = tid;
        float a[S], st[S];
        for (int s = 0; s < S; ++s) { a[s] = -__expf(A_log[i * S + s]); st[s] = 0.f; }
        float Di = Dp[i];
        for (int t = 0; t < TTOK; ++t) {
            float d = dtl[t][i];
            float ut = uu[t][i];
            float y = 0.f;
            for (int s = 0; s < S; ++s) {
                float dA = __expf(d * a[s]);
                st[s] = dA * st[s] + d * ssm[t][8 + s] * ut;
                y += st[s] * ssm[t][24 + s];
            }
            y += ut * Di;
            float g = gg[t][i];
            float sg = 1.f / (1.f + __expf(-g));
            yy[t][i] = y * g * sg;
        }
    }
    __syncthreads();
    for (int idx = tid; idx < TTOK * HDIM; idx += 256) {
        int t = idx >> 7, c = idx & 127;
        float acc = tok[t][c];
        for (int i = 0; i < 256; ++i) acc += yy[t][i] * out_w[i * 128 + c];
        hn[t][c] = acc;
    }
    __syncthreads();
    {
        int t = tid >> 5, lane = tid & 31;
        float s = 0.f;
        for (int c = lane; c < HDIM; c += 32) { float v = hn[t][c]; s += v * v; }
        for (int off = 16; off; off >>= 1) s += __shfl_down(s, off, 32);
        s = __shfl(s, 0, 32);
        float r = rsqrtf(s / HDIM + 1e-5f);
        for (int c = lane; c < HDIM; c += 32) hn[t][c] = hn[t][c] * r * normf_w[c];
    }
    __syncthreads();
    for (int c = tid; c < HDIM; c += 256) {
        float s = 0.f;
        for (int t = 0; t < TTOK; ++t) s += hn[t][c];
        GF[(size_t)b * HDIM + c] = s * (1.f / TTOK);
    }
}

// ================= final GIN + segment_sum: partial sums, 32 blocks/graph, bf16 X =================
__global__ __launch_bounds__(256) void final_partial_kernel(const ushort* __restrict__ X,
    const int* __restrict__ ssrc, const int* __restrict__ starts,
    float* __restrict__ PS)
{
    __shared__ float part[16][HDIM];
    int b = blockIdx.x >> 5;
    int j = blockIdx.x & 31;
    int tid = threadIdx.x;
    int g = tid >> 4, lane = tid & 15;
    const int c = lane * 8;
    float a0 = 0.f, a1 = 0.f, a2 = 0.f, a3 = 0.f;
    float a4 = 0.f, a5 = 0.f, a6 = 0.f, a7 = 0.f;
    {
        int nb = j * 32 + g * 2;
        for (int n = nb; n < nb + 2; ++n) {
            uint4 u = *((const uint4*)(X + ((size_t)b * NPG + n) * HDIM) + lane);
            a0 += blo(u.x); a1 += bhi(u.x); a2 += blo(u.y); a3 += bhi(u.y);
            a4 += blo(u.z); a5 += bhi(u.z); a6 += blo(u.w); a7 += bhi(u.w);
        }
    }
    {
        int e0 = starts[b * NPG], e1 = starts[(b + 1) * NPG];
        int tot = e1 - e0;
        int gi = j * 16 + g;
        int per = (tot + 511) >> 9;
        int cs = e0 + gi * per;
        int ce = min(cs + per, e1);
        for (int j0 = cs; j0 < ce; j0 += 16) {
            int myid = (j0 + lane < ce) ? ssrc[j0 + lane] : 0;
            int m = min(16, ce - j0);
            int jj = 0;
            for (; jj + 3 < m; jj += 4) {
                uint4 u[4];
                #pragma unroll
                for (int q = 0; q < 4; ++q) {
                    int sidx = __shfl(myid, jj + q, 16);
                    u[q] = *((const uint4*)(X + (size_t)sidx * HDIM) + lane);
                }
                #pragma unroll
                for (int q = 0; q < 4; ++q) {
                    a0 += blo(u[q].x); a1 += bhi(u[q].x);
                    a2 += blo(u[q].y); a3 += bhi(u[q].y);
                    a4 += blo(u[q].z); a5 += bhi(u[q].z);
                    a6 += blo(u[q].w); a7 += bhi(u[q].w);
                }
            }
            for (; jj < m; ++jj) {
                int sidx = __shfl(myid, jj, 16);
                uint4 u = *((const uint4*)(X + (size_t)sidx * HDIM) + lane);
                a0 += blo(u.x); a1 += bhi(u.x); a2 += blo(u.y); a3 += bhi(u.y);
                a4 += blo(u.z); a5 += bhi(u.z); a6 += blo(u.w); a7 += bhi(u.w);
            }
        }
    }
    part[g][c + 0] = a0; part[g][c + 1] = a1; part[g][c + 2] = a2; part[g][c + 3] = a3;
    part[g][c + 4] = a4; part[g][c + 5] = a5; part[g][c + 6] = a6; part[g][c + 7] = a7;
    __syncthreads();
    if (tid < HDIM) {
        float s = 0.f;
        for (int gg = 0; gg < 16; ++gg) s += part[gg][tid];
        atomicAdd(&PS[(size_t)b * HDIM + tid], s);
    }
}

__global__ __launch_bounds__(128) void final_mm_kernel(const float* __restrict__ PS,
    const float* __restrict__ w_out, const float* __restrict__ b_out,
    float* __restrict__ out)
{
    __shared__ float Sm[HDIM];
    int b = blockIdx.x, tid = threadIdx.x;
    Sm[tid] = PS[(size_t)b * HDIM + tid];
    __syncthreads();
    float acc = 1024.f * b_out[tid];
    for (int k = 0; k < 128; ++k) acc += Sm[k] * w_out[k * 128 + tid];
    out[(size_t)b * HDIM + tid] = acc;
}

extern "C" void kernel_launch(void* const* d_in, const int* in_sizes, int n_in,
                              void* d_out, int out_size, void* d_ws, size_t ws_size,
                              hipStream_t stream)
{
    const int N = in_sizes[0] / HDIM;      // 131072
    const int E = in_sizes[1] / 2;         // 2097152
    const int B = N >> 10;                 // 128 graphs

    const float* x_in  = (const float*)d_in[0];
    const int*   src   = (const int*)d_in[1];
    const int*   dst   = src + E;
    const float* w_in  = (const float*)d_in[5];
    const float* b_in  = (const float*)d_in[6];
    const float* gin_w = (const float*)d_in[7];
    const float* gin_b = (const float*)d_in[8];
    const float* vt    = (const float*)d_in[9];
    const float* qkv_w = (const float*)d_in[10];
    const float* qkv_b = (const float*)d_in[11];
    const float* ao_w  = (const float*)d_in[12];
    const float* ao_b  = (const float*)d_in[13];
    const float* m_in_w   = (const float*)d_in[14];
    const float* m_conv_w = (const float*)d_in[15];
    const float* m_conv_b = (const float*)d_in[16];
    const float* m_x_w    = (const float*)d_in[17];
    const float* m_dt_w   = (const float*)d_in[18];
    const float* m_dt_b   = (const float*)d_in[19];
    const float* m_A_log  = (const float*)d_in[20];
    const float* m_D      = (const float*)d_in[21];
    const float* m_out_w  = (const float*)d_in[22];
    const float* m_norm_w = (const float*)d_in[23];
    const float* m_normf_w= (const float*)d_in[24];
    const float* w_out = (const float*)d_in[25];
    const float* b_out = (const float*)d_in[26];
    float* out = (float*)d_out;

    float* GF  = (float*)d_ws;                        // B*128
    float* P   = GF + (size_t)B * HDIM;               // 2*4*8*128
    float* PART= P + 2 * 4 * TTOK * HDIM;             // B*4*PARTSZ
    int* bcursor = (int*)(PART + (size_t)B * 4 * PARTSZ);  // 512
    float* PS  = (float*)(bcursor + NBUCK);           // B*128 (adjacent -> one memset)
    uint* pairbuf = (uint*)(PS + (size_t)B * HDIM);   // NBUCK*BCAP uints
    int* count    = (int*)(pairbuf + (size_t)NBUCK * BCAP);  // N
    int* starts   = count + N;                        // N+1 (padded to N+8)
    int* ssrc     = starts + N + 8;                   // E
    ushort* XB0 = (ushort*)(ssrc + E);                // N*128 bf16
    ushort* XB1 = XB0 + (size_t)N * HDIM;             // N*128 bf16
    ushort* AGG = XB1 + (size_t)N * HDIM;             // N*128 bf16

    // ---- binned sort of edges by dst (once, reused by all 4 GINs) ----
    hipMemsetAsync(bcursor, 0, NBUCK * sizeof(int) + (size_t)B * HDIM * sizeof(float), stream);
    bin_kernel<<<(E + EPB - 1) / EPB, 256, 0, stream>>>(src, dst, bcursor, pairbuf, E);
    bucket_sort_kernel<<<NBUCK, 256, 0, stream>>>(pairbuf, bcursor, ssrc, starts, count, N);

    // ---- attention prep for both layers (independent of X) ----
    attn_prep_kernel<<<2, 256, 0, stream>>>(vt, qkv_w, qkv_b, P);

    // ---- input GIN: XB1 = (x + agg(x)) @ w_in + b_in ----
    convert_kernel<<<(N * 32 + 255) / 256, 256, 0, stream>>>(x_in, XB0, N * 32);
    gather_kernel<<<N / 16, 256, 0, stream>>>(XB0, ssrc, starts, count, AGG);
    lin128_mfma_kernel<<<N / 128, 256, 0, stream>>>(AGG, w_in, b_in, nullptr, XB1);

    ushort* Xcur = XB1;
    ushort* Xnext = XB0;
    for (int l = 0; l < 2; ++l) {
        // attention pool: 4 partial blocks/graph, then fused merge+mamba -> GF
        attn_part_kernel<<<B * 4, 256, 0, stream>>>(Xcur, P + (size_t)l * 4 * TTOK * HDIM, PART);
        mamba_kernel<<<B, 256, 0, stream>>>(PART,
                                            qkv_w + (size_t)l * 128 * 384,
                                            qkv_b + (size_t)l * 384,
                                            ao_w + (size_t)l * 128 * 128,
                                            ao_b + (size_t)l * 128,
                                            m_in_w, m_conv_w, m_conv_b, m_x_w,
                                            m_dt_w, m_dt_b, m_A_log, m_D, m_out_w,
                                            m_norm_w, m_normf_w, GF);
        // GIN: AGG = Xcur + agg(Xcur); Xnext = AGG @ gin_w + gin_b + GF[batch]
        gather_kernel<<<N / 16, 256, 0, stream>>>(Xcur, ssrc, starts, count, AGG);
        lin128_mfma_kernel<<<N / 128, 256, 0, stream>>>(AGG, gin_w + (size_t)l * 128 * 128,
                                                        gin_b + (size_t)l * 128, GF, Xnext);
        ushort* t = Xcur; Xcur = Xnext; Xnext = t;
    }

    // ---- final GIN + segment_sum: partials + tiny matmul ----
    final_partial_kernel<<<B * 32, 256, 0, stream>>>(Xcur, ssrc, starts, PS);
    final_mm_kernel<<<B, 128, 0, stream>>>(PS, w_out, b_out, out);

    (void)n_in; (void)out_size; (void)ws_size;
}